// Round 10
// baseline (114.273 us; speedup 1.0000x reference)
//
#include <hip/hip_runtime.h>

// RWKV-4 WKV forward. B=16, T=1024, C=2048, fp32.
// T-split chunked scan (z-space) + LDS-ring streaming, 16-wave blocks:
//  - block = 16 waves x 64 channels (1024 thr); segment = 64 t = 16 waves x 4 t
//  - 2 blocks/CU (LDS 79.4 KB) -> 32 waves/CU, the HW max
//  - k/v stream through a 2-slot LDS ring via global_load_lds width=16
//    (each wave loads exactly its own 4 rows -> per-wave vmcnt counting)
//  - raw s_barrier + lgkmcnt(0) (global loads stay in flight across barriers)
//  - y staged into consumed k rows, stored as 1x dwordx4 per wave/segment
// vmcnt audit (per-wave FIFO): prologue L0(2),L1(2);
//   seg s: [wait(Ls), compute, St_s(1), L_{s+2}(2)]
//   newer-than-Ls at wait: s==0 -> L1 = 2; 1<=s<=14 -> St_{s-1}+L_{s+1} = 3;
//   s==15 -> St_14 = 1.

#define T_DIM 1024
#define CDIM  2048
#define CHUNK 4
#define WAVES 16
#define SEG   (WAVES * CHUNK)   // 64
#define NSEG  (T_DIM / SEG)     // 16
#define NEG_BIG -1e38f

typedef const __attribute__((address_space(1))) float* gp_t;
typedef __attribute__((address_space(3))) float* lp_t;

__global__ __launch_bounds__(WAVES * 64, 4) void wkv_fwd_kernel(
    const float* __restrict__ w, const float* __restrict__ u,
    const float* __restrict__ kk, const float* __restrict__ vv,
    float* __restrict__ y)
{
    __shared__ __align__(16) float lk[2][SEG][64];   // 32 KB
    __shared__ __align__(16) float lv[2][SEG][64];   // 32 KB
    __shared__ float Tp[WAVES][64], Tq[WAVES][64], To[WAVES][64];  // 12 KB
    __shared__ float Sp[2][64], Sq[2][64], So[2][64];              // 1.5 KB

    const int lane = threadIdx.x & 63;
    const int wid  = threadIdx.x >> 6;
    const int b    = blockIdx.y;
    const int c0   = blockIdx.x * 64;

    const float wc  = w[c0 + lane];
    const float uc  = u[c0 + lane];
    const float wCH = wc * (float)CHUNK;

    const size_t sbase = (size_t)b * T_DIM * CDIM + c0;  // slab base (t=0)
    const int rl = lane >> 4;           // row within 4-row group
    const int cl = (lane & 15) * 4;     // col dword
    const float* kgl = kk + sbase + (size_t)rl * CDIM + cl;
    const float* vgl = vv + sbase + (size_t)rl * CDIM + cl;
    float*       ygl = y  + sbase + cl;

    if (wid == 0) { Sp[0][lane] = 0.f; Sq[0][lane] = 0.f; So[0][lane] = NEG_BIG; }

    // issue this wave's 4 rows of one segment: 1 k-load + 1 v-load (width 16)
    auto issue_seg = [&](int s) {
        const int sl = s & 1;
        const size_t go = (size_t)(s * SEG + wid * CHUNK) * CDIM;
        __builtin_amdgcn_global_load_lds((gp_t)(kgl + go),
            (lp_t)&lk[sl][wid * CHUNK][0], 16, 0, 0);
        __builtin_amdgcn_global_load_lds((gp_t)(vgl + go),
            (lp_t)&lv[sl][wid * CHUNK][0], 16, 0, 0);
    };

    issue_seg(0);
    issue_seg(1);

#pragma unroll 1
    for (int s = 0; s < NSEG; ++s) {
        const int sl = s & 1;

        // wait for MY segment-s loads (exact FIFO counts, see audit above)
        if (s == 0)            asm volatile("s_waitcnt vmcnt(2)" ::: "memory");
        else if (s == NSEG-1)  asm volatile("s_waitcnt vmcnt(1)" ::: "memory");
        else                   asm volatile("s_waitcnt vmcnt(3)" ::: "memory");
        __builtin_amdgcn_sched_barrier(0);

        // z-space precompute from LDS slot sl (own rows only)
        float uk[CHUNK], hh[CHUNK], cf[CHUNK], df[CHUNK], vc[CHUNK];
        float M = NEG_BIG;
#pragma unroll
        for (int j = 0; j < CHUNK; ++j) {
            const float kt = lk[sl][wid * CHUNK + j][lane];
            vc[j] = lv[sl][wid * CHUNK + j][lane];
            const float zj = fmaf((float)(-j), wc, kt);   // k_j - j*w
            uk[j] = uc + kt;
            const float dl = M - zj;
            cf[j] = __expf(fminf(dl, 0.f));
            df[j] = __expf(fminf(-dl, 0.f));
            hh[j] = fmaf((float)(j - 1), wc, M);
            M = fmaxf(M, zj);
        }
        float Pt = 0.f, Qt = 0.f;
#pragma unroll
        for (int j = 0; j < CHUNK; ++j) {
            Pt = fmaf(cf[j], Pt, df[j] * vc[j]);
            Qt = fmaf(cf[j], Qt, df[j]);
        }
        if (wid < WAVES - 1) {
            Tp[wid][lane] = Pt; Tq[wid][lane] = Qt;
            To[wid][lane] = fmaf((float)(CHUNK - 1), wc, M);
        }

        // barrier A: T (and S from prev segment) visible; vmem stays in flight
        asm volatile("s_waitcnt lgkmcnt(0)" ::: "memory");
        __builtin_amdgcn_s_barrier();

        // compose S_in = S_run ∘ T_0 ∘ ... ∘ T_{wid-1}
        float p = Sp[sl][lane], q = Sq[sl][lane], o = So[sl][lane];
        for (int j = 0; j < wid; ++j) {       // wave-uniform trip count
            const float Oj = To[j][lane];
            const float a  = o + wCH;
            const float d  = a - Oj;
            const float e  = __expf(-fabsf(d));
            const float sA = d >= 0.f ? 1.f : e;
            const float sB = d >= 0.f ? e : 1.f;
            p = fmaf(sA, p, sB * Tp[j][lane]);
            q = fmaf(sA, q, sB * Tq[j][lane]);
            o = fmaxf(a, Oj);
        }

        // new running state (compose result + own totals)
        if (wid == WAVES - 1) {
            const float Ot = fmaf((float)(CHUNK - 1), wc, M);
            const float a  = o + wCH;
            const float d  = a - Ot;
            const float e  = __expf(-fabsf(d));
            const float sA = d >= 0.f ? 1.f : e;
            const float sB = d >= 0.f ? e : 1.f;
            Sp[1 - sl][lane] = fmaf(sA, p, sB * Pt);
            Sq[1 - sl][lane] = fmaf(sA, q, sB * Qt);
            So[1 - sl][lane] = fmaxf(a, Ot);
        }

        // barrier B: all compose reads of T done -> T writable next segment
        asm volatile("s_waitcnt lgkmcnt(0)" ::: "memory");
        __builtin_amdgcn_s_barrier();

        // y loop: exact per-step normalizer; stage y into consumed k rows
        const int tb = s * SEG + wid * CHUNK;
        float aP = 0.f, aQ = 0.f;
#pragma unroll
        for (int j = 0; j < CHUNK; ++j) {
            const float g   = fmaf((float)j, wc, o);
            const float no  = fmaxf(fmaxf(g, hh[j]), uk[j]);
            const float ea  = __expf(g - no);
            const float eb  = __expf(hh[j] - no);
            const float ec  = __expf(uk[j] - no);
            const float num = fmaf(ea, p, fmaf(eb, aP, ec * vc[j]));
            const float den = fmaf(ea, q, fmaf(eb, aQ, ec));
            lk[sl][wid * CHUNK + j][lane] = __fdividef(num, den);
            aP = fmaf(cf[j], aP, df[j] * vc[j]);
            aQ = fmaf(cf[j], aQ, df[j]);
        }

        // y out: 1 coalesced dwordx4 store (1 vmcnt item/segment)
        {
            const float4 yv = *reinterpret_cast<const float4*>(
                &lk[sl][wid * CHUNK + rl][cl]);
            *reinterpret_cast<float4*>(ygl + (size_t)(tb + rl) * CDIM) = yv;
        }

        // end-issue segment s+2 into slot sl (all my slot-sl accesses done)
        if (s + 2 < NSEG) {
            asm volatile("s_waitcnt lgkmcnt(0)" ::: "memory");
            __builtin_amdgcn_sched_barrier(0);
            issue_seg(s + 2);
        }
    }
}

extern "C" void kernel_launch(void* const* d_in, const int* in_sizes, int n_in,
                              void* d_out, int out_size, void* d_ws, size_t ws_size,
                              hipStream_t stream) {
    // inputs: 0=B, 1=T, 2=C (scalars), 3=w[C], 4=u[C], 5=k[B*T*C], 6=v[B*T*C]
    const float* w = (const float*)d_in[3];
    const float* u = (const float*)d_in[4];
    const float* k = (const float*)d_in[5];
    const float* v = (const float*)d_in[6];
    float* y = (float*)d_out;

    const int B = in_sizes[5] / (T_DIM * CDIM);   // 16

    dim3 grid(CDIM / 64, B);
    dim3 block(WAVES * 64);
    wkv_fwd_kernel<<<grid, block, 0, stream>>>(w, u, k, v, y);
}

// Round 11
// 73.027 us; speedup vs baseline: 1.5648x; 1.5648x over previous
//
#include <hip/hip_runtime.h>

// RWKV-4 WKV forward. B=16, T=1024, C=2048, fp32.
// T-split chunked scan (z-space) + LDS-ring streaming (r9 geometry) with:
//  - NON-TEMPORAL y stores (protect k/v residency in the 256MB L3 across
//    graph replays: y writes were evicting half of k+v -> 131MB HBM fetch)
//  - double-buffered T transforms -> ONE barrier per segment
//  - prefetch of seg s+2 issued right after the z-phase frees the LDS slot
// vmcnt audit (per-wave FIFO; 4 loads mid-segment + 8 y-stores end-segment):
//   newer-than-L_s at top-of-segment wait:
//     s==0: L_1(4) = 4
//     s==1: L_2(4) + stores_0(8) = 12
//     2<=s<=14: stores_{s-2} tail(8) + L_{s+1}(4) + stores_{s-1}(8) = 20
//     s==15: stores_13(8) + stores_14(8) = 16
// Barrier audit (one s_barrier per segment, T/S double-buffered by s&1):
//   T[sl] written pre-barrier(s), read in compose(s) post-barrier(s);
//   next write of T[sl] is in seg s+2, which every wave reaches only after
//   barrier(s+1), which it reaches only after its compose(s) reads. Safe.
//   S[1-sl] written post-barrier(s) by wave 7, drained by wave 7's
//   lgkmcnt(0) before barrier(s+1); read post-barrier(s+1). Safe.

#define T_DIM 1024
#define CDIM  2048
#define CHUNK 8
#define WAVES 8
#define SEG   (WAVES * CHUNK)   // 64
#define NSEG  (T_DIM / SEG)     // 16
#define NEG_BIG -1e38f

typedef const __attribute__((address_space(1))) float* gp_t;
typedef __attribute__((address_space(3))) float* lp_t;

__global__ __launch_bounds__(WAVES * 64, 4) void wkv_fwd_kernel(
    const float* __restrict__ w, const float* __restrict__ u,
    const float* __restrict__ kk, const float* __restrict__ vv,
    float* __restrict__ y)
{
    __shared__ __align__(16) float lk[2][SEG][64];   // 32 KB
    __shared__ __align__(16) float lv[2][SEG][64];   // 32 KB
    __shared__ float Tp[2][WAVES][64], Tq[2][WAVES][64], To[2][WAVES][64]; // 12 KB
    __shared__ float Sp[2][64], Sq[2][64], So[2][64];                      // 1.5 KB

    const int lane = threadIdx.x & 63;
    const int wid  = threadIdx.x >> 6;
    const int b    = blockIdx.y;
    const int c0   = blockIdx.x * 64;

    const float wc  = w[c0 + lane];
    const float uc  = u[c0 + lane];
    const float wCH = wc * (float)CHUNK;

    const size_t sbase = (size_t)b * T_DIM * CDIM + c0;  // slab base (t=0)
    const int rl = lane >> 4;           // row within 4-row group
    const int cl = (lane & 15) * 4;     // col dword
    const float* kgl = kk + sbase + (size_t)rl * CDIM + cl;
    const float* vgl = vv + sbase + (size_t)rl * CDIM + cl;
    float*       yp  = y  + sbase + lane;   // + t*CDIM

    if (wid == 0) { Sp[0][lane] = 0.f; Sq[0][lane] = 0.f; So[0][lane] = NEG_BIG; }

    // issue this wave's 8 rows of one segment: 2 k-loads + 2 v-loads (w16)
    auto issue_seg = [&](int s) {
        const int sl = s & 1;
#pragma unroll
        for (int g = 0; g < 2; ++g) {
            const size_t go = (size_t)(s * SEG + wid * CHUNK + 4 * g) * CDIM;
            __builtin_amdgcn_global_load_lds((gp_t)(kgl + go),
                (lp_t)&lk[sl][wid * CHUNK + 4 * g][0], 16, 0, 0);
            __builtin_amdgcn_global_load_lds((gp_t)(vgl + go),
                (lp_t)&lv[sl][wid * CHUNK + 4 * g][0], 16, 0, 0);
        }
    };

    issue_seg(0);
    issue_seg(1);

#pragma unroll 1
    for (int s = 0; s < NSEG; ++s) {
        const int sl = s & 1;

        // wait for MY segment-s loads (exact FIFO counts, audit above)
        if (s == 0)            asm volatile("s_waitcnt vmcnt(4)"  ::: "memory");
        else if (s == 1)       asm volatile("s_waitcnt vmcnt(12)" ::: "memory");
        else if (s == NSEG-1)  asm volatile("s_waitcnt vmcnt(16)" ::: "memory");
        else                   asm volatile("s_waitcnt vmcnt(20)" ::: "memory");
        __builtin_amdgcn_sched_barrier(0);

        // z-space precompute from LDS slot sl (own rows only)
        float uk[CHUNK], hh[CHUNK], cf[CHUNK], df[CHUNK], vc[CHUNK];
        float M = NEG_BIG;
#pragma unroll
        for (int j = 0; j < CHUNK; ++j) {
            const float kt = lk[sl][wid * CHUNK + j][lane];
            vc[j] = lv[sl][wid * CHUNK + j][lane];
            const float zj = fmaf((float)(-j), wc, kt);   // k_j - j*w
            uk[j] = uc + kt;
            const float dl = M - zj;
            cf[j] = __expf(fminf(dl, 0.f));
            df[j] = __expf(fminf(-dl, 0.f));
            hh[j] = fmaf((float)(j - 1), wc, M);
            M = fmaxf(M, zj);
        }
        float Pt = 0.f, Qt = 0.f;
#pragma unroll
        for (int j = 0; j < CHUNK; ++j) {
            Pt = fmaf(cf[j], Pt, df[j] * vc[j]);
            Qt = fmaf(cf[j], Qt, df[j]);
        }

        // slot sl fully consumed into registers -> refill it for seg s+2
        asm volatile("s_waitcnt lgkmcnt(0)" ::: "memory");
        __builtin_amdgcn_sched_barrier(0);
        if (s + 2 < NSEG) issue_seg(s + 2);

        if (wid < WAVES - 1) {
            Tp[sl][wid][lane] = Pt; Tq[sl][wid][lane] = Qt;
            To[sl][wid][lane] = fmaf((float)(CHUNK - 1), wc, M);
        }

        // the one barrier: T(s) visible; vmem stays in flight
        asm volatile("s_waitcnt lgkmcnt(0)" ::: "memory");
        __builtin_amdgcn_s_barrier();

        // compose S_in = S_run ∘ T_0 ∘ ... ∘ T_{wid-1}
        float p = Sp[sl][lane], q = Sq[sl][lane], o = So[sl][lane];
        for (int j = 0; j < wid; ++j) {       // wave-uniform trip count
            const float Oj = To[sl][j][lane];
            const float a  = o + wCH;
            const float d  = a - Oj;
            const float e  = __expf(-fabsf(d));
            const float sA = d >= 0.f ? 1.f : e;
            const float sB = d >= 0.f ? e : 1.f;
            p = fmaf(sA, p, sB * Tp[sl][j][lane]);
            q = fmaf(sA, q, sB * Tq[sl][j][lane]);
            o = fmaxf(a, Oj);
        }

        // new running state (compose result + own totals)
        if (wid == WAVES - 1) {
            const float Ot = fmaf((float)(CHUNK - 1), wc, M);
            const float a  = o + wCH;
            const float d  = a - Ot;
            const float e  = __expf(-fabsf(d));
            const float sA = d >= 0.f ? 1.f : e;
            const float sB = d >= 0.f ? e : 1.f;
            Sp[1 - sl][lane] = fmaf(sA, p, sB * Pt);
            Sq[1 - sl][lane] = fmaf(sA, q, sB * Qt);
            So[1 - sl][lane] = fmaxf(a, Ot);
        }

        // y loop: exact per-step normalizer; direct NON-TEMPORAL stores
        const int tb = s * SEG + wid * CHUNK;
        float aP = 0.f, aQ = 0.f;
#pragma unroll
        for (int j = 0; j < CHUNK; ++j) {
            const float g   = fmaf((float)j, wc, o);
            const float no  = fmaxf(fmaxf(g, hh[j]), uk[j]);
            const float ea  = __expf(g - no);
            const float eb  = __expf(hh[j] - no);
            const float ec  = __expf(uk[j] - no);
            const float num = fmaf(ea, p, fmaf(eb, aP, ec * vc[j]));
            const float den = fmaf(ea, q, fmaf(eb, aQ, ec));
            __builtin_nontemporal_store(__fdividef(num, den),
                                        yp + (size_t)(tb + j) * CDIM);
            aP = fmaf(cf[j], aP, df[j] * vc[j]);
            aQ = fmaf(cf[j], aQ, df[j]);
        }
    }
}

extern "C" void kernel_launch(void* const* d_in, const int* in_sizes, int n_in,
                              void* d_out, int out_size, void* d_ws, size_t ws_size,
                              hipStream_t stream) {
    // inputs: 0=B, 1=T, 2=C (scalars), 3=w[C], 4=u[C], 5=k[B*T*C], 6=v[B*T*C]
    const float* w = (const float*)d_in[3];
    const float* u = (const float*)d_in[4];
    const float* k = (const float*)d_in[5];
    const float* v = (const float*)d_in[6];
    float* y = (float*)d_out;

    const int B = in_sizes[5] / (T_DIM * CDIM);   // 16

    dim3 grid(CDIM / 64, B);
    dim3 block(WAVES * 64);
    wkv_fwd_kernel<<<grid, block, 0, stream>>>(w, u, k, v, y);
}